// Round 3
// baseline (252.873 us; speedup 1.0000x reference)
//
#include <hip/hip_runtime.h>

typedef unsigned short ushort_t;
typedef __attribute__((ext_vector_type(8)))  short  short8;
typedef __attribute__((ext_vector_type(4)))  float  float4v;

#define N_NODES 4096
#define NHEADS  4
#define DK      128
#define ODIM    512
#define KDIM    512

__device__ __forceinline__ float bf2f(ushort_t u) {
    return __uint_as_float(((unsigned)u) << 16);
}
__device__ __forceinline__ ushort_t f2bf_rne(float f) {
    unsigned u = __float_as_uint(f);
    u += 0x7fffu + ((u >> 16) & 1u);
    return (ushort_t)(u >> 16);
}

// ---------------------------------------------------------------------------
// Kernel 0: input-dtype detector.  Even u16s of H: bf16 data -> sane exponent
// fields (~100%); fp32 data -> uniform mantissa bits (~20%).  flag: 1 = fp32.
// ---------------------------------------------------------------------------
__global__ __launch_bounds__(64) void detect_k(const ushort_t* __restrict__ Hraw,
                                               int* __restrict__ flag)
{
    const int lane = threadIdx.x;
    int cnt = 0;
    #pragma unroll
    for (int s = 0; s < 16; ++s) {
        ushort_t v = Hraw[(lane * 16 + s) * 2];
        int e = (v >> 7) & 0xFF;
        cnt += (((e >= 90) && (e <= 140)) || (v == 0)) ? 1 : 0;
    }
    #pragma unroll
    for (int off = 32; off; off >>= 1) cnt += __shfl_down(cnt, off);
    if (lane == 0) *flag = (cnt < 768) ? 1 : 0;
}

// ---------------------------------------------------------------------------
// Kernel 1: bit-pack mask = (A != 0) || (i == j).  64 MB -> 2 MB.
// ---------------------------------------------------------------------------
__global__ __launch_bounds__(256) void pack_mask_k(const int* __restrict__ A,
                                                   unsigned long long* __restrict__ P)
{
    int flat = blockIdx.x * 256 + threadIdx.x;
    int row  = flat >> 12;
    int col  = flat & 4095;
    int a    = A[flat];
    unsigned long long m = __ballot((a != 0) || (row == col));
    if ((threadIdx.x & 63) == 0) P[flat >> 6] = m;
}

// ---------------------------------------------------------------------------
// Kernel 2: WT[n][k] = W[k][n] as bf16 (dual-dtype input).
// ---------------------------------------------------------------------------
__global__ __launch_bounds__(256) void transpose_w_k(const void* __restrict__ W,
                                                     ushort_t* __restrict__ WT,
                                                     const int* __restrict__ flag)
{
    __shared__ ushort_t lt[64][72];
    const int f32 = *flag;
    const int tid = threadIdx.x;
    const int ti = blockIdx.x >> 3, tj = blockIdx.x & 7;
    const int r = tid >> 2, c2 = tid & 3;
    const size_t eo = (size_t)(ti * 64 + r) * KDIM + tj * 64 + c2 * 16;
    if (f32) {
        const float4v* src = (const float4v*)((const float*)W + eo);
        float4v f0 = src[0], f1 = src[1], f2 = src[2], f3 = src[3];
        #pragma unroll
        for (int e = 0; e < 4; ++e) {
            lt[r][c2 * 16 +  0 + e] = f2bf_rne(f0[e]);
            lt[r][c2 * 16 +  4 + e] = f2bf_rne(f1[e]);
            lt[r][c2 * 16 +  8 + e] = f2bf_rne(f2[e]);
            lt[r][c2 * 16 + 12 + e] = f2bf_rne(f3[e]);
        }
    } else {
        const short8* src = (const short8*)((const ushort_t*)W + eo);
        short8 v0 = src[0];
        short8 v1 = src[1];
        *(short8*)&lt[r][c2 * 16]     = v0;
        *(short8*)&lt[r][c2 * 16 + 8] = v1;
    }
    __syncthreads();
    #pragma unroll
    for (int itr = 0; itr < 2; ++itr) {
        int idx = itr * 256 + tid;
        int n = idx >> 3, c = idx & 7;
        short8 vv;
        #pragma unroll
        for (int e = 0; e < 8; ++e) vv[e] = (short)lt[c * 8 + e][n];
        *(short8*)(WT + (size_t)(tj * 64 + n) * KDIM + ti * 64 + c * 8) = vv;
    }
}

// ---------------------------------------------------------------------------
// Kernel 3: WhT[n][i] = (H @ W)[i][n].  16x16x32 MFMA, dual-dtype A loads.
// ---------------------------------------------------------------------------
__global__ __launch_bounds__(256) void gemm_wht_k(const void* __restrict__ H,
                                                  const ushort_t* __restrict__ WT,
                                                  ushort_t* __restrict__ WhT,
                                                  const int* __restrict__ flag)
{
    __shared__ ushort_t lt[64][72];
    const int f32 = *flag;
    const int tid  = threadIdx.x;
    const int lane = tid & 63;
    const int wid  = tid >> 6;
    const int quad = lane >> 4;
    const int l15  = lane & 15;
    const int bm = blockIdx.x >> 3, bn = blockIdx.x & 7;
    const int i0 = bm * 64, n0 = bn * 64;

    const size_t aoff = (size_t)(i0 + wid * 16 + l15) * KDIM + quad * 8;
    const short8* bp0 = (const short8*)(WT + (size_t)(n0 +  0 + l15) * KDIM) + quad;
    const short8* bp1 = (const short8*)(WT + (size_t)(n0 + 16 + l15) * KDIM) + quad;
    const short8* bp2 = (const short8*)(WT + (size_t)(n0 + 32 + l15) * KDIM) + quad;
    const short8* bp3 = (const short8*)(WT + (size_t)(n0 + 48 + l15) * KDIM) + quad;

    float4v acc0, acc1, acc2, acc3;
    #pragma unroll
    for (int e = 0; e < 4; ++e) { acc0[e] = 0.f; acc1[e] = 0.f; acc2[e] = 0.f; acc3[e] = 0.f; }

    #pragma unroll 4
    for (int k8 = 0; k8 < 64; k8 += 4) {
        short8 a;
        if (f32) {
            const float4v* fp = (const float4v*)((const float*)H + aoff + (size_t)k8 * 8);
            float4v x0 = fp[0], x1 = fp[1];
            #pragma unroll
            for (int e = 0; e < 4; ++e) {
                a[e]     = (short)f2bf_rne(x0[e]);
                a[4 + e] = (short)f2bf_rne(x1[e]);
            }
        } else {
            a = *(const short8*)((const ushort_t*)H + aoff + (size_t)k8 * 8);
        }
        acc0 = __builtin_amdgcn_mfma_f32_16x16x32_bf16(a, bp0[k8], acc0, 0, 0, 0);
        acc1 = __builtin_amdgcn_mfma_f32_16x16x32_bf16(a, bp1[k8], acc1, 0, 0, 0);
        acc2 = __builtin_amdgcn_mfma_f32_16x16x32_bf16(a, bp2[k8], acc2, 0, 0, 0);
        acc3 = __builtin_amdgcn_mfma_f32_16x16x32_bf16(a, bp3[k8], acc3, 0, 0, 0);
    }

    // transposed epilogue: lt[n][m] (bf16 RNE).  C/D: col=lane&15, row=quad*4+r.
    #pragma unroll
    for (int r = 0; r < 4; ++r) {
        int m = wid * 16 + quad * 4 + r;
        lt[ 0 + l15][m] = f2bf_rne(acc0[r]);
        lt[16 + l15][m] = f2bf_rne(acc1[r]);
        lt[32 + l15][m] = f2bf_rne(acc2[r]);
        lt[48 + l15][m] = f2bf_rne(acc3[r]);
    }
    __syncthreads();
    #pragma unroll
    for (int itr = 0; itr < 2; ++itr) {
        int idx = itr * 256 + tid;
        int n = idx >> 3, c = idx & 7;
        short8 v = *(const short8*)&lt[n][c * 8];
        *(short8*)(WhT + (size_t)(n0 + n) * N_NODES + i0 + c * 8) = v;
    }
}

// ---------------------------------------------------------------------------
// Kernel 4: sl[h][i], sr[h][i] from WhT (bf16) and a_l/a_r (dual-dtype).
// ---------------------------------------------------------------------------
__global__ __launch_bounds__(256) void slsr_k(const ushort_t* __restrict__ WhT,
                                              const void* __restrict__ al,
                                              const void* __restrict__ ar,
                                              float* __restrict__ sl,
                                              float* __restrict__ sr,
                                              const int* __restrict__ flag)
{
    const int f32 = *flag;
    const int b = blockIdx.x;
    const int h = b >> 4;
    const int i = ((b & 15) << 8) + threadIdx.x;
    float asl = 0.f, asr = 0.f;
    #pragma unroll 8
    for (int d = 0; d < DK; ++d) {
        float v  = bf2f(WhT[(size_t)(h * DK + d) * N_NODES + i]);
        float av = f32 ? ((const float*)al)[h * DK + d] : bf2f(((const ushort_t*)al)[h * DK + d]);
        float bv = f32 ? ((const float*)ar)[h * DK + d] : bf2f(((const ushort_t*)ar)[h * DK + d]);
        asl += v * av;
        asr += v * bv;
    }
    sl[h * N_NODES + i] = asl;
    sr[h * N_NODES + i] = asr;
}

// ---------------------------------------------------------------------------
// Kernel 5: attention.  Block = (64-row i-tile, head), 4 waves x 16 rows each.
// 16x16x32 MFMA; V double-buffered in LDS via explicit ds_write; dual-dtype out.
// ---------------------------------------------------------------------------
__global__ __launch_bounds__(256) void attn_k(const ushort_t* __restrict__ WhT,
                                              const unsigned* __restrict__ Apack,
                                              const float* __restrict__ sl,
                                              const float* __restrict__ sr,
                                              void* __restrict__ out,
                                              const int* __restrict__ flag)
{
    __shared__ ushort_t vt[2][DK][72];      // [buf][d][j+pad] 36.9 KB, rows 144 B (16-aligned)
    __shared__ float    srs[N_NODES];       // 16 KB
    __shared__ float    lsum[4][16];

    const int f32  = *flag;
    const int tid  = threadIdx.x;
    const int lane = tid & 63;
    const int wid  = tid >> 6;
    const int quad = lane >> 4;
    const int l15  = lane & 15;
    const int h    = blockIdx.x & 3;
    const int i0   = (blockIdx.x >> 2) << 6;
    const int row  = i0 + wid * 16 + l15;

    for (int j = tid; j < N_NODES; j += 256) srs[j] = sr[h * N_NODES + j];

    const float slv = sl[h * N_NODES + row];
    const float C1 = 1.44269504f;            // log2(e)
    const float C2 = 0.2f * 1.44269504f;

    float4v acc[8];
    #pragma unroll
    for (int nt = 0; nt < 8; ++nt)
        #pragma unroll
        for (int e = 0; e < 4; ++e) acc[nt][e] = 0.f;
    float lacc = 0.f;

    const int sd0 = tid >> 3;
    const int sc  = tid & 7;
    const ushort_t* gbase[4];
    #pragma unroll
    for (int q = 0; q < 4; ++q)
        gbase[q] = WhT + (size_t)(h * DK + sd0 + 32 * q) * N_NODES + sc * 8;

    short8 stg[4];
    #pragma unroll
    for (int q = 0; q < 4; ++q) stg[q] = *(const short8*)(gbase[q]);
    #pragma unroll
    for (int q = 0; q < 4; ++q) *(short8*)&vt[0][sd0 + 32 * q][sc * 8] = stg[q];
    __syncthreads();

    const unsigned* mrow = Apack + (size_t)row * 128;

    for (int it = 0; it < 64; ++it) {
        const int cur = it & 1;
        const int j0  = it << 6;
        const bool more = (it + 1) < 64;

        if (more) {
            #pragma unroll
            for (int q = 0; q < 4; ++q)
                stg[q] = *(const short8*)(gbase[q] + j0 + 64);
        }

        const unsigned w0 = mrow[it * 2];
        const unsigned w1 = mrow[it * 2 + 1];

        short8 pf[2];
        #pragma unroll
        for (int s = 0; s < 2; ++s) {
            const float4v s0 = *(const float4v*)&srs[j0 + s * 32 + quad * 8];
            const float4v s1 = *(const float4v*)&srs[j0 + s * 32 + quad * 8 + 4];
            const unsigned w = s ? w1 : w0;
            #pragma unroll
            for (int jj = 0; jj < 8; ++jj) {
                float srj = (jj < 4) ? s0[jj] : s1[jj - 4];
                float x = slv + srj;
                float t = fmaxf(x * C1, x * C2);          // leaky_relu in log2 domain
                t = ((w >> (quad * 8 + jj)) & 1u) ? t : -1e30f;
                float p = __builtin_amdgcn_exp2f(t);
                ushort_t hb = (ushort_t)(__float_as_uint(p) >> 16);   // trunc to bf16
                lacc += bf2f(hb);                          // denom matches numerator
                pf[s][jj] = (short)hb;
            }
        }

        #pragma unroll
        for (int nt = 0; nt < 8; ++nt) {
            const ushort_t* vp = &vt[cur][nt * 16 + l15][0];
            short8 b0 = *(const short8*)(vp +      quad * 8);
            short8 b1 = *(const short8*)(vp + 32 + quad * 8);
            acc[nt] = __builtin_amdgcn_mfma_f32_16x16x32_bf16(pf[0], b0, acc[nt], 0, 0, 0);
            acc[nt] = __builtin_amdgcn_mfma_f32_16x16x32_bf16(pf[1], b1, acc[nt], 0, 0, 0);
        }

        if (more) {
            #pragma unroll
            for (int q = 0; q < 4; ++q)
                *(short8*)&vt[1 - cur][sd0 + 32 * q][sc * 8] = stg[q];
        }
        __syncthreads();
    }

    // ---- epilogue: per-row denom via shuffle, normalize, elu, dual-dtype store ----
    lacc += __shfl_xor(lacc, 16);
    lacc += __shfl_xor(lacc, 32);
    if (quad == 0) lsum[wid][l15] = lacc;
    __syncthreads();

    float linv[4];
    #pragma unroll
    for (int r = 0; r < 4; ++r)
        linv[r] = 1.0f / fmaxf(lsum[wid][quad * 4 + r], 1e-37f);

    #pragma unroll
    for (int nt = 0; nt < 8; ++nt)
        #pragma unroll
        for (int r = 0; r < 4; ++r) {
            float v = acc[nt][r] * linv[r];
            float e = __builtin_amdgcn_exp2f(v * C1) - 1.0f;
            float o = (v > 0.f) ? v : e;
            size_t oidx = (size_t)(i0 + wid * 16 + quad * 4 + r) * ODIM + h * DK + nt * 16 + l15;
            if (f32) ((float*)out)[oidx] = o;
            else     ((ushort_t*)out)[oidx] = f2bf_rne(o);
        }
}

// ---------------------------------------------------------------------------
extern "C" void kernel_launch(void* const* d_in, const int* in_sizes, int n_in,
                              void* d_out, int out_size, void* d_ws, size_t ws_size,
                              hipStream_t stream)
{
    const void* H  = d_in[0];
    const int*  A  = (const int*)d_in[1];
    const void* W  = d_in[2];
    const void* al = d_in[3];
    const void* ar = d_in[4];

    if (ws_size < (7u << 20)) return;   // zero-output signature -> ws too small

    char* ws = (char*)d_ws;
    ushort_t* WhT   = (ushort_t*)ws;                                    // 4 MB
    unsigned long long* Apack = (unsigned long long*)(ws + (4u << 20)); // 2 MB
    ushort_t* WT    = (ushort_t*)(ws + (6u << 20));                     // 512 KB
    float*    sl    = (float*)(ws + (6u << 20) + (512u << 10));         // 64 KB
    float*    sr    = (float*)(ws + (6u << 20) + (576u << 10));         // 64 KB
    int*      flag  = (int*)(ws + (6u << 20) + (640u << 10));           // 4 B

    detect_k    <<<1,     64,  0, stream>>>((const ushort_t*)H, flag);
    pack_mask_k <<<65536, 256, 0, stream>>>(A, Apack);
    transpose_w_k<<<64,   256, 0, stream>>>(W, WT, flag);
    gemm_wht_k  <<<512,   256, 0, stream>>>(H, WT, WhT, flag);
    slsr_k      <<<64,    256, 0, stream>>>(WhT, al, ar, sl, sr, flag);
    attn_k      <<<256,   256, 0, stream>>>(WhT, (const unsigned*)Apack, sl, sr, (void*)d_out, flag);
}